// Round 4
// baseline (2070.127 us; speedup 1.0000x reference)
//
#include <hip/hip_runtime.h>
#include <hip/hip_cooperative_groups.h>

namespace cg = cooperative_groups;

#define NN 100000
#define NE 600000
#define DD 128
#define NL 16
#define SCAN_B 1024
#define SCAN_NB ((NN + SCAN_B - 1) / SCAN_B)   // 98

#define NBLK 256
#define NTHR 1024
#define NWAVES ((NBLK * NTHR) / 64)            // 4096
#define BASE_RPW (NN / NWAVES)                 // 24
#define REM (NN - NWAVES * BASE_RPW)           // 1696
#define RPW_MAX (BASE_RPW + 1)                 // 25

// --- CSR build ---------------------------------------------------------------

__global__ void k_deg(const int* __restrict__ ei, int* __restrict__ deg) {
    int e = blockIdx.x * blockDim.x + threadIdx.x;
    if (e < NE) atomicAdd(&deg[ei[e]], 1);
}

__global__ void k_dis(const int* __restrict__ deg, float* __restrict__ dis) {
    int i = blockIdx.x * blockDim.x + threadIdx.x;
    if (i >= NN) return;
    int d = deg[i];
    dis[i] = d > 0 ? rsqrtf((float)d) : 0.f;
}

__global__ void k_bsum(const int* __restrict__ cnt, int* __restrict__ bsum) {
    __shared__ int sh[SCAN_B];
    int i = blockIdx.x * SCAN_B + threadIdx.x;
    sh[threadIdx.x] = (i < NN) ? cnt[i] : 0;
    __syncthreads();
    for (int off = SCAN_B / 2; off > 0; off >>= 1) {
        if (threadIdx.x < off) sh[threadIdx.x] += sh[threadIdx.x + off];
        __syncthreads();
    }
    if (threadIdx.x == 0) bsum[blockIdx.x] = sh[0];
}

__global__ void k_bscan(int* __restrict__ bsum) {
    if (threadIdx.x == 0) {
        int run = 0;
        for (int i = 0; i < SCAN_NB; ++i) { int v = bsum[i]; bsum[i] = run; run += v; }
    }
}

__global__ void k_scan2(const int* __restrict__ cnt, const int* __restrict__ bsum,
                        int* __restrict__ rowptr) {
    __shared__ int sh[SCAN_B];
    int i = blockIdx.x * SCAN_B + threadIdx.x;
    sh[threadIdx.x] = (i < NN) ? cnt[i] : 0;
    __syncthreads();
    for (int off = 1; off < SCAN_B; off <<= 1) {
        int t = (threadIdx.x >= off) ? sh[threadIdx.x - off] : 0;
        __syncthreads();
        sh[threadIdx.x] += t;
        __syncthreads();
    }
    if (i < NN) rowptr[i + 1] = bsum[blockIdx.x] + sh[threadIdx.x];
    if (blockIdx.x == 0 && threadIdx.x == 0) rowptr[0] = 0;
}

__global__ void k_fill(const int* __restrict__ ei, const float* __restrict__ dis,
                       const int* __restrict__ rowptr, int* __restrict__ cursor,
                       int2* __restrict__ edges) {
    int e = blockIdx.x * blockDim.x + threadIdx.x;
    if (e >= NE) return;
    int r = ei[e], c = ei[NE + e];
    float v = dis[r] * dis[c];
    int pos = rowptr[r] + atomicAdd(&cursor[r], 1);
    edges[pos] = make_int2(c, __float_as_int(v));
}

// --- persistent cooperative mega-kernel --------------------------------------
// acc (per-row coefficients of x_l) lives in registers for all 16 layers.
// `out` doubles as the negative-edge accumulator, then receives the final blend.
__global__ __launch_bounds__(NTHR, 4) void k_mega(
    const int* __restrict__ rowptr, const int2* __restrict__ edges,
    const int* __restrict__ negei, const float* __restrict__ feat,
    float* __restrict__ xa, float* __restrict__ xb, float* __restrict__ out)
{
    cg::grid_group grid = cg::this_grid();
    const int gt = blockIdx.x * blockDim.x + threadIdx.x;
    const int wave = gt >> 6;
    const int lane = gt & 63;
    const int d2 = lane * 2;
    const int r0 = wave * BASE_RPW + (wave < REM ? wave : REM);
    const int nrows = BASE_RPW + (wave < REM ? 1 : 0);

    float2 acc[RPW_MAX];
#pragma unroll
    for (int j = 0; j < RPW_MAX; ++j) acc[j] = make_float2(0.f, 0.f);

    const double cc = 120.0 / 100000.0 + 2.0;
    double b = 1.0, bn = 1.0;

    for (int l = 0; l < NL; ++l) {
        const float* __restrict__ xo = (l == 0) ? feat : ((l & 1) ? xb : xa);
        float* __restrict__ xn = (l & 1) ? xa : xb;
        const float fb = (float)b;
        const float coef =
            (float)(0.5 * ((1.0 - bn) + 2.0 * bn / cc) + (l > 0 ? 0.5 : 0.0));

        // negative-edge scatter into `out` (<=120 rows, trivial)
        if (gt < 120 * 32) {
            const int* nl_ = negei + l * 120;
            int e = gt >> 5;
            int d4 = (gt & 31) << 2;
            int rr = nl_[e];
            int nc = (e < 60) ? nl_[60 + e] : nl_[e - 60];
            float nco = (float)(-0.5 * bn / cc);
            const float4 xv = *reinterpret_cast<const float4*>(xo + (size_t)nc * DD + d4);
            float* ap = out + (size_t)rr * DD + d4;
            atomicAdd(ap + 0, nco * xv.x);
            atomicAdd(ap + 1, nco * xv.y);
            atomicAdd(ap + 2, nco * xv.z);
            atomicAdd(ap + 3, nco * xv.w);
        }

#pragma unroll
        for (int j = 0; j < RPW_MAX; ++j) {
            if (j < nrows) {
                const int r = r0 + j;
                int p = rowptr[r];
                const int end = rowptr[r + 1];
                float2 sum = make_float2(0.f, 0.f);
                for (; p + 1 < end; p += 2) {
                    int2 e0 = edges[p];
                    int2 e1 = edges[p + 1];
                    float v0 = __int_as_float(e0.y);
                    float v1 = __int_as_float(e1.y);
                    const float2 g0 = *reinterpret_cast<const float2*>(xo + (size_t)e0.x * DD + d2);
                    const float2 g1 = *reinterpret_cast<const float2*>(xo + (size_t)e1.x * DD + d2);
                    sum.x += v0 * g0.x + v1 * g1.x;
                    sum.y += v0 * g0.y + v1 * g1.y;
                }
                if (p < end) {
                    int2 ev = edges[p];
                    float v = __int_as_float(ev.y);
                    const float2 gv = *reinterpret_cast<const float2*>(xo + (size_t)ev.x * DD + d2);
                    sum.x += v * gv.x;
                    sum.y += v * gv.y;
                }
                const size_t i = (size_t)r * DD + d2;
                const float2 o = *reinterpret_cast<const float2*>(xo + i);
                float2 n;
                n.x = (1.f - fb) * o.x + fb * sum.x;
                n.y = (1.f - fb) * o.y + fb * sum.y;
                acc[j].x += coef * o.x;
                acc[j].y += coef * o.y;
                if (l == NL - 1) {
                    acc[j].x += 0.5f * n.x;
                    acc[j].y += 0.5f * n.y;
                } else {
                    *reinterpret_cast<float2*>(xn + i) = n;
                }
            }
        }
        b *= 0.9;
        bn *= 0.5;
        grid.sync();
    }

    // out = ALPHA*feat + ((1-ALPHA)/16)*(acc + neg_acc_in_out)
    const float s = 0.85f / 16.f;
#pragma unroll
    for (int j = 0; j < RPW_MAX; ++j) {
        if (j < nrows) {
            const size_t i = (size_t)(r0 + j) * DD + d2;
            const float2 f = *reinterpret_cast<const float2*>(feat + i);
            const float2 ng = *reinterpret_cast<const float2*>(out + i);
            float2 o2;
            o2.x = 0.15f * f.x + s * (acc[j].x + ng.x);
            o2.y = 0.15f * f.y + s * (acc[j].y + ng.y);
            *reinterpret_cast<float2*>(out + i) = o2;
        }
    }
}

extern "C" void kernel_launch(void* const* d_in, const int* in_sizes, int n_in,
                              void* d_out, int out_size, void* d_ws, size_t ws_size,
                              hipStream_t stream) {
    const float* feat = (const float*)d_in[0];
    const int* ei = (const int*)d_in[1];
    const int* negei = (const int*)d_in[2];
    float* out = (float*)d_out;

    float* x0 = (float*)d_ws;                        // NN*DD f32
    float* x1 = x0 + (size_t)NN * DD;                // NN*DD f32
    int2* edges = (int2*)(x1 + (size_t)NN * DD);     // NE int2
    int* rowptr = (int*)(edges + NE);                // NN+1
    int* deg = rowptr + (NN + 1);                    // NN (reused as cursor)
    float* dis = (float*)(deg + NN);                 // NN
    int* bsum = (int*)(dis + NN);                    // SCAN_NB

    const size_t xbytes = (size_t)NN * DD * sizeof(float);

    hipMemsetAsync(deg, 0, NN * sizeof(int), stream);
    hipMemsetAsync(out, 0, xbytes, stream);

    k_deg<<<(NE + 255) / 256, 256, 0, stream>>>(ei, deg);
    k_dis<<<(NN + 255) / 256, 256, 0, stream>>>(deg, dis);
    k_bsum<<<SCAN_NB, SCAN_B, 0, stream>>>(deg, bsum);
    k_bscan<<<1, 64, 0, stream>>>(bsum);
    k_scan2<<<SCAN_NB, SCAN_B, 0, stream>>>(deg, bsum, rowptr);
    hipMemsetAsync(deg, 0, NN * sizeof(int), stream);   // deg -> cursor
    k_fill<<<(NE + 255) / 256, 256, 0, stream>>>(ei, dis, rowptr, deg, edges);

    void* args[] = { (void*)&rowptr, (void*)&edges, (void*)&negei, (void*)&feat,
                     (void*)&x0, (void*)&x1, (void*)&out };
    hipLaunchCooperativeKernel((const void*)k_mega, dim3(NBLK), dim3(NTHR),
                               args, 0, stream);
}

// Round 7
// 1145.735 us; speedup vs baseline: 1.8068x; 1.8068x over previous
//
#include <hip/hip_runtime.h>

#define NN 100000
#define NE 600000
#define DD 128
#define NL 16
#define SCAN_B 1024
#define SCAN_NB ((NN + SCAN_B - 1) / SCAN_B)   // 98

// --- CSR build ---------------------------------------------------------------

__global__ void k_deg(const int* __restrict__ ei, int* __restrict__ deg) {
    int e = blockIdx.x * blockDim.x + threadIdx.x;
    if (e < NE) atomicAdd(&deg[ei[e]], 1);
}

__global__ void k_dis(const int* __restrict__ deg, float* __restrict__ dis) {
    int i = blockIdx.x * blockDim.x + threadIdx.x;
    if (i >= NN) return;
    int d = deg[i];
    dis[i] = d > 0 ? rsqrtf((float)d) : 0.f;
}

__global__ void k_bsum(const int* __restrict__ cnt, int* __restrict__ bsum) {
    __shared__ int sh[SCAN_B];
    int i = blockIdx.x * SCAN_B + threadIdx.x;
    sh[threadIdx.x] = (i < NN) ? cnt[i] : 0;
    __syncthreads();
    for (int off = SCAN_B / 2; off > 0; off >>= 1) {
        if (threadIdx.x < off) sh[threadIdx.x] += sh[threadIdx.x + off];
        __syncthreads();
    }
    if (threadIdx.x == 0) bsum[blockIdx.x] = sh[0];
}

__global__ void k_bscan(int* __restrict__ bsum) {
    if (threadIdx.x == 0) {
        int run = 0;
        for (int i = 0; i < SCAN_NB; ++i) { int v = bsum[i]; bsum[i] = run; run += v; }
    }
}

__global__ void k_scan2(const int* __restrict__ cnt, const int* __restrict__ bsum,
                        int* __restrict__ rowptr) {
    __shared__ int sh[SCAN_B];
    int i = blockIdx.x * SCAN_B + threadIdx.x;
    sh[threadIdx.x] = (i < NN) ? cnt[i] : 0;
    __syncthreads();
    for (int off = 1; off < SCAN_B; off <<= 1) {
        int t = (threadIdx.x >= off) ? sh[threadIdx.x - off] : 0;
        __syncthreads();
        sh[threadIdx.x] += t;
        __syncthreads();
    }
    if (i < NN) rowptr[i + 1] = bsum[blockIdx.x] + sh[threadIdx.x];
    if (blockIdx.x == 0 && threadIdx.x == 0) rowptr[0] = 0;
}

__global__ void k_fill(const int* __restrict__ ei, const float* __restrict__ dis,
                       const int* __restrict__ rowptr, int* __restrict__ cursor,
                       int2* __restrict__ edges) {
    int e = blockIdx.x * blockDim.x + threadIdx.x;
    if (e >= NE) return;
    int r = ei[e], c = ei[NE + e];
    float v = dis[r] * dis[c];
    int pos = rowptr[r] + atomicAdd(&cursor[r], 1);
    edges[pos] = make_int2(c, __float_as_int(v));
}

// --- per-layer fused kernel --------------------------------------------------
// MODE 0: xn only (odd layers 1..13)
// MODE 1: xn + acc WRITE c0*o + c1*n   (layer 0 — acc may hold poison, no read)
// MODE 2: xn + acc += c0*o + c1*n      (even layers 2..14)
// MODE 3: final (layer 15): acc(=out) = 0.15*feat + c0*(acc + 0.5*n); no xn
template<int MODE>
__global__ __launch_bounds__(256) void k_layer(const int* __restrict__ rowptr,
                                               const int2* __restrict__ edges,
                                               const float* __restrict__ xo,
                                               float* __restrict__ xn,
                                               float* __restrict__ acc,
                                               const float* __restrict__ feat,
                                               float fb, float c0, float c1) {
    int wave = threadIdx.x >> 6;
    int lane = threadIdx.x & 63;
    int r = blockIdx.x * 4 + wave;
    if (r >= NN) return;
    int p = rowptr[r];
    const int end = rowptr[r + 1];
    const int d2 = lane * 2;
    float sx = 0.f, sy = 0.f;
    for (; p + 3 < end; p += 4) {
        int2 e0 = edges[p];
        int2 e1 = edges[p + 1];
        int2 e2 = edges[p + 2];
        int2 e3 = edges[p + 3];
        float v0 = __int_as_float(e0.y);
        float v1 = __int_as_float(e1.y);
        float v2 = __int_as_float(e2.y);
        float v3 = __int_as_float(e3.y);
        const float2 g0 = *reinterpret_cast<const float2*>(xo + (size_t)e0.x * DD + d2);
        const float2 g1 = *reinterpret_cast<const float2*>(xo + (size_t)e1.x * DD + d2);
        const float2 g2 = *reinterpret_cast<const float2*>(xo + (size_t)e2.x * DD + d2);
        const float2 g3 = *reinterpret_cast<const float2*>(xo + (size_t)e3.x * DD + d2);
        sx += v0 * g0.x + v1 * g1.x + v2 * g2.x + v3 * g3.x;
        sy += v0 * g0.y + v1 * g1.y + v2 * g2.y + v3 * g3.y;
    }
    for (; p < end; ++p) {
        int2 ev = edges[p];
        float v = __int_as_float(ev.y);
        const float2 gv = *reinterpret_cast<const float2*>(xo + (size_t)ev.x * DD + d2);
        sx += v * gv.x;
        sy += v * gv.y;
    }
    const size_t i = (size_t)r * DD + d2;
    const float2 o = *reinterpret_cast<const float2*>(xo + i);
    float nx = (1.f - fb) * o.x + fb * sx;
    float ny = (1.f - fb) * o.y + fb * sy;
    if (MODE == 3) {
        const float2 f = *reinterpret_cast<const float2*>(feat + i);
        const float2 a = *reinterpret_cast<const float2*>(acc + i);
        float2 o2;
        o2.x = 0.15f * f.x + c0 * (a.x + 0.5f * nx);
        o2.y = 0.15f * f.y + c0 * (a.y + 0.5f * ny);
        *reinterpret_cast<float2*>(acc + i) = o2;
    } else {
        *reinterpret_cast<float2*>(xn + i) = make_float2(nx, ny);
        if (MODE == 1) {
            float2 a;
            a.x = c0 * o.x + c1 * nx;
            a.y = c0 * o.y + c1 * ny;
            *reinterpret_cast<float2*>(acc + i) = a;
        } else if (MODE == 2) {
            float2 a = *reinterpret_cast<float2*>(acc + i);
            a.x += c0 * o.x + c1 * nx;
            a.y += c0 * o.y + c1 * ny;
            *reinterpret_cast<float2*>(acc + i) = a;
        }
    }
}

// acc[nr] += coef * x[nc] over the 120 mirrored negative edges of this layer
__global__ void k_neg(const int* __restrict__ nl, const float* __restrict__ x,
                      float* __restrict__ acc, float coef) {
    int tid = blockIdx.x * blockDim.x + threadIdx.x;
    int e = tid >> 5;
    if (e >= 120) return;
    int d4 = (tid & 31) << 2;
    int r = nl[e];
    int c = (e < 60) ? nl[60 + e] : nl[e - 60];
    const float4 xv = *reinterpret_cast<const float4*>(x + (size_t)c * DD + d4);
    float* ap = acc + (size_t)r * DD + d4;
    atomicAdd(ap + 0, coef * xv.x);
    atomicAdd(ap + 1, coef * xv.y);
    atomicAdd(ap + 2, coef * xv.z);
    atomicAdd(ap + 3, coef * xv.w);
}

extern "C" void kernel_launch(void* const* d_in, const int* in_sizes, int n_in,
                              void* d_out, int out_size, void* d_ws, size_t ws_size,
                              hipStream_t stream) {
    const float* feat = (const float*)d_in[0];
    const int* ei = (const int*)d_in[1];
    const int* negei = (const int*)d_in[2];
    float* out = (float*)d_out;

    float* xa = (float*)d_ws;                        // NN*DD f32 (x1,x3,...)
    float* xb = xa + (size_t)NN * DD;                // NN*DD f32 (x2,x4,...)
    int2* edges = (int2*)(xb + (size_t)NN * DD);     // NE int2
    int* rowptr = (int*)(edges + NE);                // NN+1
    int* deg = rowptr + (NN + 1);                    // NN (reused as cursor)
    float* dis = (float*)(deg + NN);                 // NN
    int* bsum = (int*)(dis + NN);                    // SCAN_NB

    hipMemsetAsync(deg, 0, NN * sizeof(int), stream);
    k_deg<<<(NE + 255) / 256, 256, 0, stream>>>(ei, deg);
    k_dis<<<(NN + 255) / 256, 256, 0, stream>>>(deg, dis);
    k_bsum<<<SCAN_NB, SCAN_B, 0, stream>>>(deg, bsum);
    k_bscan<<<1, 64, 0, stream>>>(bsum);
    k_scan2<<<SCAN_NB, SCAN_B, 0, stream>>>(deg, bsum, rowptr);
    hipMemsetAsync(deg, 0, NN * sizeof(int), stream);   // deg -> cursor
    k_fill<<<(NE + 255) / 256, 256, 0, stream>>>(ei, dis, rowptr, deg, edges);

    // host-side coefficient tables (double precision)
    const double cc = 120.0 / 100000.0 + 2.0;
    double bv[NL], coef[NL + 1], negco[NL];
    {
        double b = 1.0, bn = 1.0;
        for (int l = 0; l < NL; ++l) {
            double al = (1.0 - bn) + 2.0 * bn / cc;
            bv[l] = b;
            coef[l] = 0.5 * al + (l > 0 ? 0.5 : 0.0);
            negco[l] = -0.5 * bn / cc;
            b *= 0.9;
            bn *= 0.5;
        }
    }

    const int lg = (NN + 3) / 4;   // 4 rows (waves) per 256-thr block

    // x_l buffer for l>=1: (l&1) ? xa : xb
    for (int l = 0; l < NL - 1; ++l) {
        const float* xo = (l == 0) ? feat : ((l & 1) ? xa : xb);
        float* xn = (l & 1) ? xb : xa;
        float fb = (float)bv[l];
        if (l == 0) {
            k_layer<1><<<lg, 256, 0, stream>>>(rowptr, edges, xo, xn, out, feat,
                                               fb, (float)coef[0], (float)coef[1]);
        } else if ((l & 1) == 0) {
            k_layer<2><<<lg, 256, 0, stream>>>(rowptr, edges, xo, xn, out, feat,
                                               fb, (float)coef[l], (float)coef[l + 1]);
        } else {
            k_layer<0><<<lg, 256, 0, stream>>>(rowptr, edges, xo, xn, out, feat,
                                               fb, 0.f, 0.f);
        }
        k_neg<<<(120 * 32 + 255) / 256, 256, 0, stream>>>(negei + l * 120, xo, out,
                                                          (float)negco[l]);
    }
    // layer 15: neg first (uses x15), then fused final
    {
        const float* xo = xa;   // x15 (15&1 -> xa)
        k_neg<<<(120 * 32 + 255) / 256, 256, 0, stream>>>(negei + 15 * 120, xo, out,
                                                          (float)negco[15]);
        k_layer<3><<<lg, 256, 0, stream>>>(rowptr, edges, xo, nullptr, out, feat,
                                           (float)bv[15], 0.85f / 16.f, 0.f);
    }
}

// Round 8
// 1117.879 us; speedup vs baseline: 1.8518x; 1.0249x over previous
//
#include <hip/hip_runtime.h>

#define NN 100000
#define NE 600000
#define DD 128
#define NL 16
#define SCAN_B 1024
#define SCAN_NB ((NN + SCAN_B - 1) / SCAN_B)   // 98

// --- CSR build ---------------------------------------------------------------

__global__ void k_deg(const int* __restrict__ ei, int* __restrict__ deg) {
    int e = blockIdx.x * blockDim.x + threadIdx.x;
    if (e < NE) atomicAdd(&deg[ei[e]], 1);
}

__global__ void k_dis(const int* __restrict__ deg, float* __restrict__ dis) {
    int i = blockIdx.x * blockDim.x + threadIdx.x;
    if (i >= NN) return;
    int d = deg[i];
    dis[i] = d > 0 ? rsqrtf((float)d) : 0.f;
}

__global__ void k_bsum(const int* __restrict__ cnt, int* __restrict__ bsum) {
    __shared__ int sh[SCAN_B];
    int i = blockIdx.x * SCAN_B + threadIdx.x;
    sh[threadIdx.x] = (i < NN) ? cnt[i] : 0;
    __syncthreads();
    for (int off = SCAN_B / 2; off > 0; off >>= 1) {
        if (threadIdx.x < off) sh[threadIdx.x] += sh[threadIdx.x + off];
        __syncthreads();
    }
    if (threadIdx.x == 0) bsum[blockIdx.x] = sh[0];
}

__global__ void k_bscan(int* __restrict__ bsum) {
    if (threadIdx.x == 0) {
        int run = 0;
        for (int i = 0; i < SCAN_NB; ++i) { int v = bsum[i]; bsum[i] = run; run += v; }
    }
}

__global__ void k_scan2(const int* __restrict__ cnt, const int* __restrict__ bsum,
                        int* __restrict__ rowptr) {
    __shared__ int sh[SCAN_B];
    int i = blockIdx.x * SCAN_B + threadIdx.x;
    sh[threadIdx.x] = (i < NN) ? cnt[i] : 0;
    __syncthreads();
    for (int off = 1; off < SCAN_B; off <<= 1) {
        int t = (threadIdx.x >= off) ? sh[threadIdx.x - off] : 0;
        __syncthreads();
        sh[threadIdx.x] += t;
        __syncthreads();
    }
    if (i < NN) rowptr[i + 1] = bsum[blockIdx.x] + sh[threadIdx.x];
    if (blockIdx.x == 0 && threadIdx.x == 0) rowptr[0] = 0;
}

__global__ void k_fill(const int* __restrict__ ei, const float* __restrict__ dis,
                       const int* __restrict__ rowptr, int* __restrict__ cursor,
                       int2* __restrict__ edges) {
    int e = blockIdx.x * blockDim.x + threadIdx.x;
    if (e >= NE) return;
    int r = ei[e], c = ei[NE + e];
    float v = dis[r] * dis[c];
    int pos = rowptr[r] + atomicAdd(&cursor[r], 1);
    edges[pos] = make_int2(c, __float_as_int(v));
}

// --- per-layer fused kernel (one row per 32-lane half-wave, float4/lane) -----
// MODE 0: xn only (odd layers 1..13)
// MODE 1: xn + acc WRITE c0*o + c1*n   (layer 0 — acc holds poison, no read)
// MODE 2: xn + acc += c0*o + c1*n      (even layers 2..14)
// MODE 3: final (layer 15): acc(=out) = 0.15*feat + c0*(acc + 0.5*n); no xn
template<int MODE>
__global__ __launch_bounds__(256) void k_layer(const int* __restrict__ rowptr,
                                               const int2* __restrict__ edges,
                                               const float* __restrict__ xo,
                                               float* __restrict__ xn,
                                               float* __restrict__ acc,
                                               const float* __restrict__ feat,
                                               float fb, float c0, float c1) {
    const int hw = threadIdx.x >> 5;        // 0..7 half-waves per block
    const int lane = threadIdx.x & 31;
    const int r = blockIdx.x * 8 + hw;
    if (r >= NN) return;
    int p = rowptr[r];
    const int end = rowptr[r + 1];
    const int d4 = lane * 4;
    float4 s = make_float4(0.f, 0.f, 0.f, 0.f);
    for (; p + 3 < end; p += 4) {
        int2 e0 = edges[p];
        int2 e1 = edges[p + 1];
        int2 e2 = edges[p + 2];
        int2 e3 = edges[p + 3];
        float v0 = __int_as_float(e0.y);
        float v1 = __int_as_float(e1.y);
        float v2 = __int_as_float(e2.y);
        float v3 = __int_as_float(e3.y);
        const float4 g0 = *reinterpret_cast<const float4*>(xo + (size_t)e0.x * DD + d4);
        const float4 g1 = *reinterpret_cast<const float4*>(xo + (size_t)e1.x * DD + d4);
        const float4 g2 = *reinterpret_cast<const float4*>(xo + (size_t)e2.x * DD + d4);
        const float4 g3 = *reinterpret_cast<const float4*>(xo + (size_t)e3.x * DD + d4);
        s.x += v0 * g0.x + v1 * g1.x + v2 * g2.x + v3 * g3.x;
        s.y += v0 * g0.y + v1 * g1.y + v2 * g2.y + v3 * g3.y;
        s.z += v0 * g0.z + v1 * g1.z + v2 * g2.z + v3 * g3.z;
        s.w += v0 * g0.w + v1 * g1.w + v2 * g2.w + v3 * g3.w;
    }
    for (; p < end; ++p) {
        int2 ev = edges[p];
        float v = __int_as_float(ev.y);
        const float4 gv = *reinterpret_cast<const float4*>(xo + (size_t)ev.x * DD + d4);
        s.x += v * gv.x;
        s.y += v * gv.y;
        s.z += v * gv.z;
        s.w += v * gv.w;
    }
    const size_t i = (size_t)r * DD + d4;
    const float4 o = *reinterpret_cast<const float4*>(xo + i);
    float4 n;
    n.x = (1.f - fb) * o.x + fb * s.x;
    n.y = (1.f - fb) * o.y + fb * s.y;
    n.z = (1.f - fb) * o.z + fb * s.z;
    n.w = (1.f - fb) * o.w + fb * s.w;
    if (MODE == 3) {
        const float4 f = *reinterpret_cast<const float4*>(feat + i);
        const float4 a = *reinterpret_cast<const float4*>(acc + i);
        float4 o2;
        o2.x = 0.15f * f.x + c0 * (a.x + 0.5f * n.x);
        o2.y = 0.15f * f.y + c0 * (a.y + 0.5f * n.y);
        o2.z = 0.15f * f.z + c0 * (a.z + 0.5f * n.z);
        o2.w = 0.15f * f.w + c0 * (a.w + 0.5f * n.w);
        *reinterpret_cast<float4*>(acc + i) = o2;
    } else {
        *reinterpret_cast<float4*>(xn + i) = n;
        if (MODE == 1) {
            float4 a;
            a.x = c0 * o.x + c1 * n.x;
            a.y = c0 * o.y + c1 * n.y;
            a.z = c0 * o.z + c1 * n.z;
            a.w = c0 * o.w + c1 * n.w;
            *reinterpret_cast<float4*>(acc + i) = a;
        } else if (MODE == 2) {
            float4 a = *reinterpret_cast<float4*>(acc + i);
            a.x += c0 * o.x + c1 * n.x;
            a.y += c0 * o.y + c1 * n.y;
            a.z += c0 * o.z + c1 * n.z;
            a.w += c0 * o.w + c1 * n.w;
            *reinterpret_cast<float4*>(acc + i) = a;
        }
    }
}

// acc[nr] += coef * x[nc] over the 120 mirrored negative edges of this layer
__global__ void k_neg(const int* __restrict__ nl, const float* __restrict__ x,
                      float* __restrict__ acc, float coef) {
    int tid = blockIdx.x * blockDim.x + threadIdx.x;
    int e = tid >> 5;
    if (e >= 120) return;
    int d4 = (tid & 31) << 2;
    int r = nl[e];
    int c = (e < 60) ? nl[60 + e] : nl[e - 60];
    const float4 xv = *reinterpret_cast<const float4*>(x + (size_t)c * DD + d4);
    float* ap = acc + (size_t)r * DD + d4;
    atomicAdd(ap + 0, coef * xv.x);
    atomicAdd(ap + 1, coef * xv.y);
    atomicAdd(ap + 2, coef * xv.z);
    atomicAdd(ap + 3, coef * xv.w);
}

extern "C" void kernel_launch(void* const* d_in, const int* in_sizes, int n_in,
                              void* d_out, int out_size, void* d_ws, size_t ws_size,
                              hipStream_t stream) {
    const float* feat = (const float*)d_in[0];
    const int* ei = (const int*)d_in[1];
    const int* negei = (const int*)d_in[2];
    float* out = (float*)d_out;

    float* xa = (float*)d_ws;                        // NN*DD f32 (x1,x3,...)
    float* xb = xa + (size_t)NN * DD;                // NN*DD f32 (x2,x4,...)
    int2* edges = (int2*)(xb + (size_t)NN * DD);     // NE int2
    int* rowptr = (int*)(edges + NE);                // NN+1
    int* deg = rowptr + (NN + 1);                    // NN (reused as cursor)
    float* dis = (float*)(deg + NN);                 // NN
    int* bsum = (int*)(dis + NN);                    // SCAN_NB

    hipMemsetAsync(deg, 0, NN * sizeof(int), stream);
    k_deg<<<(NE + 255) / 256, 256, 0, stream>>>(ei, deg);
    k_dis<<<(NN + 255) / 256, 256, 0, stream>>>(deg, dis);
    k_bsum<<<SCAN_NB, SCAN_B, 0, stream>>>(deg, bsum);
    k_bscan<<<1, 64, 0, stream>>>(bsum);
    k_scan2<<<SCAN_NB, SCAN_B, 0, stream>>>(deg, bsum, rowptr);
    hipMemsetAsync(deg, 0, NN * sizeof(int), stream);   // deg -> cursor
    k_fill<<<(NE + 255) / 256, 256, 0, stream>>>(ei, dis, rowptr, deg, edges);

    // host-side coefficient tables (double precision)
    const double cc = 120.0 / 100000.0 + 2.0;
    double bv[NL], coef[NL + 1], negco[NL];
    {
        double b = 1.0, bn = 1.0;
        for (int l = 0; l < NL; ++l) {
            double al = (1.0 - bn) + 2.0 * bn / cc;
            bv[l] = b;
            coef[l] = 0.5 * al + (l > 0 ? 0.5 : 0.0);
            negco[l] = -0.5 * bn / cc;
            b *= 0.9;
            bn *= 0.5;
        }
    }

    const int lg = (NN + 7) / 8;   // 8 rows (half-waves) per 256-thr block

    // x_l buffer for l>=1: (l&1) ? xa : xb
    for (int l = 0; l < NL - 1; ++l) {
        const float* xo = (l == 0) ? feat : ((l & 1) ? xa : xb);
        float* xn = (l & 1) ? xb : xa;
        float fb = (float)bv[l];
        if (l == 0) {
            k_layer<1><<<lg, 256, 0, stream>>>(rowptr, edges, xo, xn, out, feat,
                                               fb, (float)coef[0], (float)coef[1]);
        } else if ((l & 1) == 0) {
            k_layer<2><<<lg, 256, 0, stream>>>(rowptr, edges, xo, xn, out, feat,
                                               fb, (float)coef[l], (float)coef[l + 1]);
        } else {
            k_layer<0><<<lg, 256, 0, stream>>>(rowptr, edges, xo, xn, out, feat,
                                               fb, 0.f, 0.f);
        }
        k_neg<<<(120 * 32 + 255) / 256, 256, 0, stream>>>(negei + l * 120, xo, out,
                                                          (float)negco[l]);
    }
    // layer 15: neg first (uses x15), then fused final
    {
        const float* xo = xa;   // x15 (15&1 -> xa)
        k_neg<<<(120 * 32 + 255) / 256, 256, 0, stream>>>(negei + 15 * 120, xo, out,
                                                          (float)negco[15]);
        k_layer<3><<<lg, 256, 0, stream>>>(rowptr, edges, xo, nullptr, out, feat,
                                           (float)bv[15], 0.85f / 16.f, 0.f);
    }
}

// Round 9
// 725.904 us; speedup vs baseline: 2.8518x; 1.5400x over previous
//
#include <hip/hip_runtime.h>
#include <hip/hip_fp16.h>

#define NN 100000
#define NE 600000
#define DD 128
#define NL 16
#define SCAN_B 1024
#define SCAN_NB ((NN + SCAN_B - 1) / SCAN_B)   // 98

// --- CSR build ---------------------------------------------------------------

__global__ void k_deg(const int* __restrict__ ei, int* __restrict__ deg) {
    int e = blockIdx.x * blockDim.x + threadIdx.x;
    if (e < NE) atomicAdd(&deg[ei[e]], 1);
}

__global__ void k_dis(const int* __restrict__ deg, float* __restrict__ dis) {
    int i = blockIdx.x * blockDim.x + threadIdx.x;
    if (i >= NN) return;
    int d = deg[i];
    dis[i] = d > 0 ? rsqrtf((float)d) : 0.f;
}

__global__ void k_bsum(const int* __restrict__ cnt, int* __restrict__ bsum) {
    __shared__ int sh[SCAN_B];
    int i = blockIdx.x * SCAN_B + threadIdx.x;
    sh[threadIdx.x] = (i < NN) ? cnt[i] : 0;
    __syncthreads();
    for (int off = SCAN_B / 2; off > 0; off >>= 1) {
        if (threadIdx.x < off) sh[threadIdx.x] += sh[threadIdx.x + off];
        __syncthreads();
    }
    if (threadIdx.x == 0) bsum[blockIdx.x] = sh[0];
}

__global__ void k_bscan(int* __restrict__ bsum) {
    if (threadIdx.x == 0) {
        int run = 0;
        for (int i = 0; i < SCAN_NB; ++i) { int v = bsum[i]; bsum[i] = run; run += v; }
    }
}

__global__ void k_scan2(const int* __restrict__ cnt, const int* __restrict__ bsum,
                        int* __restrict__ rowptr) {
    __shared__ int sh[SCAN_B];
    int i = blockIdx.x * SCAN_B + threadIdx.x;
    sh[threadIdx.x] = (i < NN) ? cnt[i] : 0;
    __syncthreads();
    for (int off = 1; off < SCAN_B; off <<= 1) {
        int t = (threadIdx.x >= off) ? sh[threadIdx.x - off] : 0;
        __syncthreads();
        sh[threadIdx.x] += t;
        __syncthreads();
    }
    if (i < NN) rowptr[i + 1] = bsum[blockIdx.x] + sh[threadIdx.x];
    if (blockIdx.x == 0 && threadIdx.x == 0) rowptr[0] = 0;
}

__global__ void k_fill(const int* __restrict__ ei, const float* __restrict__ dis,
                       const int* __restrict__ rowptr, int* __restrict__ cursor,
                       int2* __restrict__ edges) {
    int e = blockIdx.x * blockDim.x + threadIdx.x;
    if (e >= NE) return;
    int r = ei[e], c = ei[NE + e];
    float v = dis[r] * dis[c];
    int pos = rowptr[r] + atomicAdd(&cursor[r], 1);
    edges[pos] = make_int2(c, __float_as_int(v));
}

// feat f32 -> fp16
__global__ void k_cvt(const float* __restrict__ f, __half* __restrict__ h) {
    int i = blockIdx.x * blockDim.x + threadIdx.x;   // 4 floats each
    const float4 v = reinterpret_cast<const float4*>(f)[i];
    __half2 a = __floats2half2_rn(v.x, v.y);
    __half2 b = __floats2half2_rn(v.z, v.w);
    uint2 o;
    o.x = *reinterpret_cast<uint*>(&a);
    o.y = *reinterpret_cast<uint*>(&b);
    reinterpret_cast<uint2*>(h)[i] = o;
}

__device__ __forceinline__ void acc8(float* s, uint4 g, float v) {
    const __half2* h = reinterpret_cast<const __half2*>(&g);
    float2 f0 = __half22float2(h[0]);
    float2 f1 = __half22float2(h[1]);
    float2 f2 = __half22float2(h[2]);
    float2 f3 = __half22float2(h[3]);
    s[0] += v * f0.x; s[1] += v * f0.y; s[2] += v * f1.x; s[3] += v * f1.y;
    s[4] += v * f2.x; s[5] += v * f2.y; s[6] += v * f3.x; s[7] += v * f3.y;
}

// --- per-layer fused kernel (one row per 16-lane quarter-wave, 16B/lane) -----
// MODE 0: xn only (odd layers 1..13)
// MODE 1: xn + acc WRITE c0*o + c1*n   (layer 0 — acc holds poison, no read)
// MODE 2: xn + acc += c0*o + c1*n      (even layers 2..14)
// MODE 3: final (layer 15): acc(=out) = 0.15*feat + c0*(acc + 0.5*n); no xn
template<int MODE>
__global__ __launch_bounds__(256) void k_layer(const int* __restrict__ rowptr,
                                               const int2* __restrict__ edges,
                                               const __half* __restrict__ xo,
                                               __half* __restrict__ xn,
                                               float* __restrict__ acc,
                                               const float* __restrict__ feat,
                                               float fb, float c0, float c1) {
    const int qw = threadIdx.x >> 4;        // 0..15 quarter-waves per block
    const int lane = threadIdx.x & 15;
    const int r = blockIdx.x * 16 + qw;
    if (r >= NN) return;
    int p = rowptr[r];
    const int end = rowptr[r + 1];
    const int d8 = lane * 8;                // half index
    float s[8] = {0.f, 0.f, 0.f, 0.f, 0.f, 0.f, 0.f, 0.f};
    for (; p + 3 < end; p += 4) {
        int2 e0 = edges[p];
        int2 e1 = edges[p + 1];
        int2 e2 = edges[p + 2];
        int2 e3 = edges[p + 3];
        const uint4 g0 = *reinterpret_cast<const uint4*>(xo + (size_t)e0.x * DD + d8);
        const uint4 g1 = *reinterpret_cast<const uint4*>(xo + (size_t)e1.x * DD + d8);
        const uint4 g2 = *reinterpret_cast<const uint4*>(xo + (size_t)e2.x * DD + d8);
        const uint4 g3 = *reinterpret_cast<const uint4*>(xo + (size_t)e3.x * DD + d8);
        acc8(s, g0, __int_as_float(e0.y));
        acc8(s, g1, __int_as_float(e1.y));
        acc8(s, g2, __int_as_float(e2.y));
        acc8(s, g3, __int_as_float(e3.y));
    }
    for (; p < end; ++p) {
        int2 ev = edges[p];
        const uint4 gv = *reinterpret_cast<const uint4*>(xo + (size_t)ev.x * DD + d8);
        acc8(s, gv, __int_as_float(ev.y));
    }
    const size_t ih = (size_t)r * DD + d8;        // half index
    const uint4 ou = *reinterpret_cast<const uint4*>(xo + ih);
    float o[8];
    {
        const __half2* h = reinterpret_cast<const __half2*>(&ou);
        float2 f0 = __half22float2(h[0]);
        float2 f1 = __half22float2(h[1]);
        float2 f2 = __half22float2(h[2]);
        float2 f3 = __half22float2(h[3]);
        o[0] = f0.x; o[1] = f0.y; o[2] = f1.x; o[3] = f1.y;
        o[4] = f2.x; o[5] = f2.y; o[6] = f3.x; o[7] = f3.y;
    }
    float n[8];
#pragma unroll
    for (int k = 0; k < 8; ++k) n[k] = (1.f - fb) * o[k] + fb * s[k];

    if (MODE == 3) {
        const float4 fA = *reinterpret_cast<const float4*>(feat + ih);
        const float4 fB = *reinterpret_cast<const float4*>(feat + ih + 4);
        const float4 aA = *reinterpret_cast<const float4*>(acc + ih);
        const float4 aB = *reinterpret_cast<const float4*>(acc + ih + 4);
        float4 oA, oB;
        oA.x = 0.15f * fA.x + c0 * (aA.x + 0.5f * n[0]);
        oA.y = 0.15f * fA.y + c0 * (aA.y + 0.5f * n[1]);
        oA.z = 0.15f * fA.z + c0 * (aA.z + 0.5f * n[2]);
        oA.w = 0.15f * fA.w + c0 * (aA.w + 0.5f * n[3]);
        oB.x = 0.15f * fB.x + c0 * (aB.x + 0.5f * n[4]);
        oB.y = 0.15f * fB.y + c0 * (aB.y + 0.5f * n[5]);
        oB.z = 0.15f * fB.z + c0 * (aB.z + 0.5f * n[6]);
        oB.w = 0.15f * fB.w + c0 * (aB.w + 0.5f * n[7]);
        *reinterpret_cast<float4*>(acc + ih) = oA;
        *reinterpret_cast<float4*>(acc + ih + 4) = oB;
    } else {
        __half2 p0 = __floats2half2_rn(n[0], n[1]);
        __half2 p1 = __floats2half2_rn(n[2], n[3]);
        __half2 p2 = __floats2half2_rn(n[4], n[5]);
        __half2 p3 = __floats2half2_rn(n[6], n[7]);
        uint4 w;
        w.x = *reinterpret_cast<uint*>(&p0);
        w.y = *reinterpret_cast<uint*>(&p1);
        w.z = *reinterpret_cast<uint*>(&p2);
        w.w = *reinterpret_cast<uint*>(&p3);
        *reinterpret_cast<uint4*>(xn + ih) = w;
        if (MODE == 1) {
            float4 aA, aB;
            aA.x = c0 * o[0] + c1 * n[0];
            aA.y = c0 * o[1] + c1 * n[1];
            aA.z = c0 * o[2] + c1 * n[2];
            aA.w = c0 * o[3] + c1 * n[3];
            aB.x = c0 * o[4] + c1 * n[4];
            aB.y = c0 * o[5] + c1 * n[5];
            aB.z = c0 * o[6] + c1 * n[6];
            aB.w = c0 * o[7] + c1 * n[7];
            *reinterpret_cast<float4*>(acc + ih) = aA;
            *reinterpret_cast<float4*>(acc + ih + 4) = aB;
        } else if (MODE == 2) {
            float4 aA = *reinterpret_cast<const float4*>(acc + ih);
            float4 aB = *reinterpret_cast<const float4*>(acc + ih + 4);
            aA.x += c0 * o[0] + c1 * n[0];
            aA.y += c0 * o[1] + c1 * n[1];
            aA.z += c0 * o[2] + c1 * n[2];
            aA.w += c0 * o[3] + c1 * n[3];
            aB.x += c0 * o[4] + c1 * n[4];
            aB.y += c0 * o[5] + c1 * n[5];
            aB.z += c0 * o[6] + c1 * n[6];
            aB.w += c0 * o[7] + c1 * n[7];
            *reinterpret_cast<float4*>(acc + ih) = aA;
            *reinterpret_cast<float4*>(acc + ih + 4) = aB;
        }
    }
}

// acc[nr] += coef * x[nc] over the 120 mirrored negative edges of this layer
__global__ void k_neg(const int* __restrict__ nl, const __half* __restrict__ x,
                      float* __restrict__ acc, float coef) {
    int tid = blockIdx.x * blockDim.x + threadIdx.x;
    int e = tid >> 5;
    if (e >= 120) return;
    int d4 = (tid & 31) << 2;
    int r = nl[e];
    int c = (e < 60) ? nl[60 + e] : nl[e - 60];
    const uint2 g = *reinterpret_cast<const uint2*>(x + (size_t)c * DD + d4);
    const __half2* h = reinterpret_cast<const __half2*>(&g);
    float2 f0 = __half22float2(h[0]);
    float2 f1 = __half22float2(h[1]);
    float* ap = acc + (size_t)r * DD + d4;
    atomicAdd(ap + 0, coef * f0.x);
    atomicAdd(ap + 1, coef * f0.y);
    atomicAdd(ap + 2, coef * f1.x);
    atomicAdd(ap + 3, coef * f1.y);
}

extern "C" void kernel_launch(void* const* d_in, const int* in_sizes, int n_in,
                              void* d_out, int out_size, void* d_ws, size_t ws_size,
                              hipStream_t stream) {
    const float* feat = (const float*)d_in[0];
    const int* ei = (const int*)d_in[1];
    const int* negei = (const int*)d_in[2];
    float* out = (float*)d_out;

    __half* xh0 = (__half*)d_ws;                     // NN*DD half (feat cvt)
    __half* xha = xh0 + (size_t)NN * DD;             // NN*DD half
    __half* xhb = xha + (size_t)NN * DD;             // NN*DD half
    int2* edges = (int2*)(xhb + (size_t)NN * DD);    // NE int2
    int* rowptr = (int*)(edges + NE);                // NN+1
    int* deg = rowptr + (NN + 1);                    // NN (reused as cursor)
    float* dis = (float*)(deg + NN);                 // NN
    int* bsum = (int*)(dis + NN);                    // SCAN_NB

    hipMemsetAsync(deg, 0, NN * sizeof(int), stream);
    k_deg<<<(NE + 255) / 256, 256, 0, stream>>>(ei, deg);
    k_dis<<<(NN + 255) / 256, 256, 0, stream>>>(deg, dis);
    k_bsum<<<SCAN_NB, SCAN_B, 0, stream>>>(deg, bsum);
    k_bscan<<<1, 64, 0, stream>>>(bsum);
    k_scan2<<<SCAN_NB, SCAN_B, 0, stream>>>(deg, bsum, rowptr);
    hipMemsetAsync(deg, 0, NN * sizeof(int), stream);   // deg -> cursor
    k_fill<<<(NE + 255) / 256, 256, 0, stream>>>(ei, dis, rowptr, deg, edges);
    k_cvt<<<(NN * DD / 4) / 256, 256, 0, stream>>>(feat, xh0);

    // host-side coefficient tables (double precision)
    const double cc = 120.0 / 100000.0 + 2.0;
    double bv[NL], coef[NL + 1], negco[NL];
    {
        double b = 1.0, bn = 1.0;
        for (int l = 0; l < NL; ++l) {
            double al = (1.0 - bn) + 2.0 * bn / cc;
            bv[l] = b;
            coef[l] = 0.5 * al + (l > 0 ? 0.5 : 0.0);
            negco[l] = -0.5 * bn / cc;
            b *= 0.9;
            bn *= 0.5;
        }
    }

    const int lg = (NN + 15) / 16;   // 16 rows (quarter-waves) per 256-thr block

    for (int l = 0; l < NL - 1; ++l) {
        const __half* xo = (l == 0) ? xh0 : ((l & 1) ? xha : xhb);
        __half* xn = (l & 1) ? xhb : xha;
        float fb = (float)bv[l];
        if (l == 0) {
            k_layer<1><<<lg, 256, 0, stream>>>(rowptr, edges, xo, xn, out, feat,
                                               fb, (float)coef[0], (float)coef[1]);
        } else if ((l & 1) == 0) {
            k_layer<2><<<lg, 256, 0, stream>>>(rowptr, edges, xo, xn, out, feat,
                                               fb, (float)coef[l], (float)coef[l + 1]);
        } else {
            k_layer<0><<<lg, 256, 0, stream>>>(rowptr, edges, xo, xn, out, feat,
                                               fb, 0.f, 0.f);
        }
        k_neg<<<(120 * 32 + 255) / 256, 256, 0, stream>>>(negei + l * 120, xo, out,
                                                          (float)negco[l]);
    }
    // layer 15: neg first (uses x15), then fused final
    {
        const __half* xo = xha;   // x15 (15&1 -> xha)
        k_neg<<<(120 * 32 + 255) / 256, 256, 0, stream>>>(negei + 15 * 120, xo, out,
                                                          (float)negco[15]);
        k_layer<3><<<lg, 256, 0, stream>>>(rowptr, edges, xo, nullptr, out, feat,
                                           (float)bv[15], 0.85f / 16.f, 0.f);
    }
}